// Round 2
// baseline (1394.179 us; speedup 1.0000x reference)
//
#include <hip/hip_runtime.h>
#include <hip/hip_bf16.h>

#define HID 128

static inline int cdiv_i(long a, long b) { return (int)((a + b - 1) / b); }

// ---------------------------------------------------------------------------
// GEMM: C[M x 128] = A[M x 128] @ W[128 x 128], fp32.
// 256 threads/block, 128 rows/block. Each thread: 8 rows x 8 cols acc.
// k chunked by 32: wl = 32x128 (16KB), al = 128x36 (18KB) -> 34.8KB LDS.
// ---------------------------------------------------------------------------
__global__ __launch_bounds__(256) void gemm128(const float* __restrict__ A,
                                               const float* __restrict__ W,
                                               float* __restrict__ C, int M) {
    __shared__ float wl[32 * 128];
    __shared__ float al[128 * 36];
    const int tid = threadIdx.x;
    const long row0 = (long)blockIdx.x * 128;
    const int cg = tid & 15;
    const int rg4 = (tid >> 4) * 4;
    const int c0 = cg * 4;

    float acc[8][8];
#pragma unroll
    for (int r = 0; r < 8; ++r)
#pragma unroll
        for (int c = 0; c < 8; ++c) acc[r][c] = 0.f;

    for (int kb = 0; kb < 128; kb += 32) {
        __syncthreads();
        {
            const float4* Wg = (const float4*)(W + kb * 128);
            float4* wl4 = (float4*)wl;
#pragma unroll
            for (int i = 0; i < 4; ++i) wl4[tid + 256 * i] = Wg[tid + 256 * i];
        }
        {
            const int r = tid >> 1;
            const int half = (tid & 1) * 16;
            const long row = row0 + r;
            float* dst = al + r * 36 + half;
            if (row < M) {
                const float4* src = (const float4*)(A + row * 128 + kb + half);
#pragma unroll
                for (int i = 0; i < 4; ++i) ((float4*)dst)[i] = src[i];
            } else {
                float4 z = make_float4(0.f, 0.f, 0.f, 0.f);
#pragma unroll
                for (int i = 0; i < 4; ++i) ((float4*)dst)[i] = z;
            }
        }
        __syncthreads();

#pragma unroll
        for (int kk = 0; kk < 32; kk += 4) {
            float4 w0[4], w1[4];
#pragma unroll
            for (int j = 0; j < 4; ++j) {
                w0[j] = *(const float4*)(wl + (kk + j) * 128 + c0);
                w1[j] = *(const float4*)(wl + (kk + j) * 128 + c0 + 64);
            }
#pragma unroll
            for (int g = 0; g < 8; ++g) {
                const int rr = ((g & 4) ? 64 : 0) + rg4 + (g & 3);
                float4 av = *(const float4*)(al + rr * 36 + kk);
                float* ac = acc[g];
                float aj;
                aj = av.x;
                ac[0] += aj * w0[0].x; ac[1] += aj * w0[0].y; ac[2] += aj * w0[0].z; ac[3] += aj * w0[0].w;
                ac[4] += aj * w1[0].x; ac[5] += aj * w1[0].y; ac[6] += aj * w1[0].z; ac[7] += aj * w1[0].w;
                aj = av.y;
                ac[0] += aj * w0[1].x; ac[1] += aj * w0[1].y; ac[2] += aj * w0[1].z; ac[3] += aj * w0[1].w;
                ac[4] += aj * w1[1].x; ac[5] += aj * w1[1].y; ac[6] += aj * w1[1].z; ac[7] += aj * w1[1].w;
                aj = av.z;
                ac[0] += aj * w0[2].x; ac[1] += aj * w0[2].y; ac[2] += aj * w0[2].z; ac[3] += aj * w0[2].w;
                ac[4] += aj * w1[2].x; ac[5] += aj * w1[2].y; ac[6] += aj * w1[2].z; ac[7] += aj * w1[2].w;
                aj = av.w;
                ac[0] += aj * w0[3].x; ac[1] += aj * w0[3].y; ac[2] += aj * w0[3].z; ac[3] += aj * w0[3].w;
                ac[4] += aj * w1[3].x; ac[5] += aj * w1[3].y; ac[6] += aj * w1[3].z; ac[7] += aj * w1[3].w;
            }
        }
    }

#pragma unroll
    for (int g = 0; g < 8; ++g) {
        const int rr = ((g & 4) ? 64 : 0) + rg4 + (g & 3);
        const long row = row0 + rr;
        if (row < M) {
            float* cp = C + row * 128;
            *(float4*)(cp + c0) = make_float4(acc[g][0], acc[g][1], acc[g][2], acc[g][3]);
            *(float4*)(cp + c0 + 64) = make_float4(acc[g][4], acc[g][5], acc[g][6], acc[g][7]);
        }
    }
}

// ---------------------------------------------------------------------------
// Attention scores: as[i] = h[i] . asrc, ad[i] = h[i] . adst. 1 wave / node.
// ---------------------------------------------------------------------------
__global__ __launch_bounds__(256) void att_scores(const float* __restrict__ h,
                                                  const float* __restrict__ aw_s,
                                                  const float* __restrict__ aw_d,
                                                  float* __restrict__ as_o,
                                                  float* __restrict__ ad_o, int M) {
    const int node = blockIdx.x * 4 + (threadIdx.x >> 6);
    const int lane = threadIdx.x & 63;
    if (node >= M) return;
    const float h0 = h[(size_t)node * 128 + lane];
    const float h1 = h[(size_t)node * 128 + 64 + lane];
    float s = h0 * aw_s[lane] + h1 * aw_s[64 + lane];
    float d = h0 * aw_d[lane] + h1 * aw_d[64 + lane];
#pragma unroll
    for (int o = 32; o > 0; o >>= 1) {
        s += __shfl_down(s, o);
        d += __shfl_down(d, o);
    }
    if (lane == 0) { as_o[node] = s; ad_o[node] = d; }
}

// ---------------------------------------------------------------------------
// CSR build: count -> scan -> fill. Self loops appended implicitly.
// ---------------------------------------------------------------------------
__global__ void csr_count(const int* __restrict__ dst, int E, int M, int* cnt) {
    const int i = blockIdx.x * 256 + threadIdx.x;
    if (i >= E + M) return;
    const int d = (i < E) ? dst[i] : (i - E);
    atomicAdd(&cnt[d], 1);
}

__global__ void csr_fill(const int* __restrict__ src, const int* __restrict__ dst,
                         int E, int M, const int* __restrict__ offs, int* cur,
                         int* __restrict__ srcl) {
    const int i = blockIdx.x * 256 + threadIdx.x;
    if (i >= E + M) return;
    int s, d;
    if (i < E) { s = src[i]; d = dst[i]; } else { s = i - E; d = i - E; }
    const int pos = atomicAdd(&cur[d], 1);
    srcl[offs[d] + pos] = s;
}

// ---------------------------------------------------------------------------
// 3-phase exclusive scan (int). out has n+1 entries.
// ---------------------------------------------------------------------------
__global__ __launch_bounds__(1024) void scan_tile(const int* __restrict__ in,
                                                  int* __restrict__ out,
                                                  int* __restrict__ bsum, int n) {
    __shared__ int buf[1024];
    const int tid = threadIdx.x;
    const int i = blockIdx.x * 1024 + tid;
    const int v = (i < n) ? in[i] : 0;
    buf[tid] = v;
    __syncthreads();
    int x = v;
    for (int o = 1; o < 1024; o <<= 1) {
        const int t = (tid >= o) ? buf[tid - o] : 0;
        __syncthreads();
        x += t;
        buf[tid] = x;
        __syncthreads();
    }
    if (i < n) out[i] = x - v;
    if (tid == 1023) bsum[blockIdx.x] = x;
}

__global__ __launch_bounds__(1024) void scan_single(int* __restrict__ bsum, int nb) {
    __shared__ int buf[1024];
    const int tid = threadIdx.x;
    const int v = (tid < nb) ? bsum[tid] : 0;
    buf[tid] = v;
    __syncthreads();
    int x = v;
    for (int o = 1; o < 1024; o <<= 1) {
        const int t = (tid >= o) ? buf[tid - o] : 0;
        __syncthreads();
        x += t;
        buf[tid] = x;
        __syncthreads();
    }
    if (tid < nb) bsum[tid] = x - v;
    if (tid == 1023) bsum[nb] = x;
}

__global__ void scan_add(int* __restrict__ out, const int* __restrict__ bsum,
                         int n, int nb) {
    const int i = blockIdx.x * 256 + threadIdx.x;
    if (i < n) out[i] += bsum[i >> 10];
    else if (i == n) out[i] = bsum[nb];
}

// ---------------------------------------------------------------------------
// GAT aggregation: 1 wave/node, 2 feats/lane.
// ---------------------------------------------------------------------------
__global__ __launch_bounds__(256) void gat_agg(const float* __restrict__ h,
                                               const float* __restrict__ av_s,
                                               const float* __restrict__ av_d,
                                               const int* __restrict__ offs,
                                               const int* __restrict__ srcl,
                                               const float* __restrict__ bias,
                                               float* __restrict__ out, int M) {
    const int node = blockIdx.x * 4 + (threadIdx.x >> 6);
    const int lane = threadIdx.x & 63;
    if (node >= M) return;
    const int beg = offs[node], end = offs[node + 1];
    const float adv = av_d[node];
    float m = -1e30f;
    for (int j = beg; j < end; ++j) {
        float e = av_s[srcl[j]] + adv;
        e = (e > 0.f) ? e : 0.2f * e;
        m = fmaxf(m, e);
    }
    float denom = 0.f, a0 = 0.f, a1 = 0.f;
    for (int j = beg; j < end; ++j) {
        const int s = srcl[j];
        float e = av_s[s] + adv;
        e = (e > 0.f) ? e : 0.2f * e;
        const float w = __expf(e - m);
        denom += w;
        const float2 hv = *(const float2*)(h + (size_t)s * 128 + lane * 2);
        a0 += w * hv.x;
        a1 += w * hv.y;
    }
    const float inv = 1.f / denom;
    const float2 bv = *(const float2*)(bias + lane * 2);
    *(float2*)(out + (size_t)node * 128 + lane * 2) =
        make_float2(a0 * inv + bv.x, a1 * inv + bv.y);
}

// ---------------------------------------------------------------------------
// GCN degree norm + aggregation
// ---------------------------------------------------------------------------
__global__ void deg_inv(const int* __restrict__ cnt, float* __restrict__ dinv, int M) {
    const int i = blockIdx.x * 256 + threadIdx.x;
    if (i < M) dinv[i] = rsqrtf(fmaxf((float)cnt[i], 1e-12f));
}

__global__ __launch_bounds__(256) void gcn_agg(const float* __restrict__ xw,
                                               const float* __restrict__ dinv,
                                               const int* __restrict__ offs,
                                               const int* __restrict__ srcl,
                                               const float* __restrict__ bias,
                                               float* __restrict__ out, int M) {
    const int node = blockIdx.x * 4 + (threadIdx.x >> 6);
    const int lane = threadIdx.x & 63;
    if (node >= M) return;
    const int beg = offs[node], end = offs[node + 1];
    const float dv = dinv[node];
    float a0 = 0.f, a1 = 0.f;
    for (int j = beg; j < end; ++j) {
        const int s = srcl[j];
        const float nw = dv * dinv[s];
        const float2 hv = *(const float2*)(xw + (size_t)s * 128 + lane * 2);
        a0 += nw * hv.x;
        a1 += nw * hv.y;
    }
    const float2 bv = *(const float2*)(bias + lane * 2);
    *(float2*)(out + (size_t)node * 128 + lane * 2) = make_float2(a0 + bv.x, a1 + bv.y);
}

// ---------------------------------------------------------------------------
// Row gather: out[i][:] = tab[idx[i]][:]  (float4 per thread, 32/row)
// ---------------------------------------------------------------------------
__global__ void gather_rows(const float* __restrict__ tab, const int* __restrict__ idx,
                            float* __restrict__ out, int n) {
    const long t = (long)blockIdx.x * 256 + threadIdx.x;
    if (t >= (long)n * 32) return;
    const int row = (int)(t >> 5);
    const int c = (int)(t & 31);
    const int srow = idx[row];
    ((float4*)out)[(long)row * 32 + c] = ((const float4*)tab)[(long)srow * 32 + c];
}

__global__ void copy_vec(const float* __restrict__ src, float* __restrict__ dst, int n) {
    const int i = blockIdx.x * 256 + threadIdx.x;
    if (i < n) dst[i] = src[i];
}

// ---------------------------------------------------------------------------
// Cosine similarity: 1 wave/graph
// ---------------------------------------------------------------------------
__global__ __launch_bounds__(256) void cosine_k(const float* __restrict__ lf,
                                                const float* __restrict__ rf,
                                                float* __restrict__ out, int B) {
    const int g = blockIdx.x * 4 + (threadIdx.x >> 6);
    const int lane = threadIdx.x & 63;
    if (g >= B) return;
    const float2 a = *(const float2*)(lf + (size_t)g * 128 + lane * 2);
    const float2 b = *(const float2*)(rf + (size_t)g * 128 + lane * 2);
    float num = a.x * b.x + a.y * b.y;
    float na = a.x * a.x + a.y * a.y;
    float nb = b.x * b.x + b.y * b.y;
#pragma unroll
    for (int o = 32; o > 0; o >>= 1) {
        num += __shfl_down(num, o);
        na += __shfl_down(na, o);
        nb += __shfl_down(nb, o);
    }
    if (lane == 0)
        out[g] = num / (fmaxf(sqrtf(na), 1e-6f) * fmaxf(sqrtf(nb), 1e-6f));
}

// ---------------------------------------------------------------------------
extern "C" void kernel_launch(void* const* d_in, const int* in_sizes, int n_in,
                              void* d_out, int out_size, void* d_ws, size_t ws_size,
                              hipStream_t stream) {
    (void)n_in; (void)ws_size;
    // d_in follows setup_inputs() DICT order (not reference-signature order):
    // 31: left_x, 32: right_x, 33: left_graph_index, 34: right_graph_index,
    // 35: left_x_batch, 36: right_x_batch, 37: num_graphs
    const float* spec = (const float*)d_in[0];
    const float* tabs[3] = {(const float*)d_in[1], (const float*)d_in[2], (const float*)d_in[3]};
    const float* ontW[3] = {(const float*)d_in[4], (const float*)d_in[8], (const float*)d_in[12]};
    const float* ontAs[3] = {(const float*)d_in[5], (const float*)d_in[9], (const float*)d_in[13]};
    const float* ontAd[3] = {(const float*)d_in[6], (const float*)d_in[10], (const float*)d_in[14]};
    const float* ontB[3] = {(const float*)d_in[7], (const float*)d_in[11], (const float*)d_in[15]};
    const float* gcnW[3] = {(const float*)d_in[16], (const float*)d_in[18], (const float*)d_in[20]};
    const float* gcnB[3] = {(const float*)d_in[17], (const float*)d_in[19], (const float*)d_in[21]};
    const int* e1s[3] = {(const int*)d_in[22], (const int*)d_in[24], (const int*)d_in[26]};
    const int* e2s[3] = {(const int*)d_in[23], (const int*)d_in[25], (const int*)d_in[27]};
    const int* maps[3] = {(const int*)d_in[28], (const int*)d_in[29], (const int*)d_in[30]};
    const int* left_x = (const int*)d_in[31];
    const int* right_x = (const int*)d_in[32];
    const int* left_eg = (const int*)d_in[33];
    const int* right_eg = (const int*)d_in[34];
    const int* left_batch = (const int*)d_in[35];
    const int* right_batch = (const int*)d_in[36];

    int Ms[3] = {in_sizes[1] / HID, in_sizes[2] / HID, in_sizes[3] / HID};
    int E1s[3] = {in_sizes[22] / 2, in_sizes[24] / 2, in_sizes[26] / 2};
    int E2s[3] = {in_sizes[23] / 2, in_sizes[25] / 2, in_sizes[27] / 2};
    int Ls[3] = {in_sizes[28], in_sizes[29], in_sizes[30]};
    const int NP = in_sizes[31];       // patient nodes per side
    const int EP = in_sizes[33] / 2;   // patient edges per side
    const int B = out_size;            // num graphs
    const int ALL = 1 + Ls[0] + Ls[1] + Ls[2];

    int maxM = Ms[0], maxT = 0;
    for (int i = 0; i < 3; ++i) {
        if (Ms[i] > maxM) maxM = Ms[i];
        int t1 = E1s[i] + Ms[i], t2 = E2s[i] + Ms[i];
        if (t1 > maxT) maxT = t1;
        if (t2 > maxT) maxT = t2;
    }

    char* ws = (char*)d_ws;
    size_t off = 0;
    auto alloc = [&](size_t bytes) -> void* {
        off = (off + 255) & ~(size_t)255;
        void* p = ws + off;
        off += bytes;
        return p;
    };

    // permanent
    float* allemb = (float*)alloc((size_t)ALL * HID * 4);
    float* lf = (float*)alloc((size_t)B * HID * 4);
    float* rf = (float*)alloc((size_t)B * HID * 4);
    int* gcnt = (int*)alloc((size_t)B * 4);
    int* gstart = (int*)alloc((size_t)(B + 1) * 4);
    int* bsum = (int*)alloc(1025 * 4);
    const size_t off0 = off;

    // ontology scratch (phase 1)
    float* oH = (float*)alloc((size_t)maxM * HID * 4);
    float* oE = (float*)alloc((size_t)maxM * HID * 4);
    float* oAs = (float*)alloc((size_t)maxM * 4);
    float* oAd = (float*)alloc((size_t)maxM * 4);
    int* oCnt = (int*)alloc((size_t)maxM * 4);
    int* oOffs = (int*)alloc((size_t)(maxM + 1) * 4);
    int* oCur = (int*)alloc((size_t)maxM * 4);
    int* oSrcl = (int*)alloc((size_t)maxT * 4);

    // patient scratch (phase 2, overlaps phase 1 — stream-ordered reuse)
    off = off0;
    float* xbuf = (float*)alloc((size_t)NP * HID * 4);
    float* xw = (float*)alloc((size_t)NP * HID * 4);
    float* dinv = (float*)alloc((size_t)NP * 4);
    int* pCnt = (int*)alloc((size_t)NP * 4);
    int* pOffs = (int*)alloc((size_t)(NP + 1) * 4);
    int* pCur = (int*)alloc((size_t)NP * 4);
    int* pSrcl = (int*)alloc((size_t)(EP + NP) * 4);

    auto scan_excl = [&](const int* in, int* out, int n) {
        const int nb = cdiv_i(n, 1024);
        scan_tile<<<nb, 1024, 0, stream>>>(in, out, bsum, n);
        scan_single<<<1, 1024, 0, stream>>>(bsum, nb);
        scan_add<<<cdiv_i(n + 1, 256), 256, 0, stream>>>(out, bsum, n, nb);
    };

    // spec_emb -> all_emb row 0
    copy_vec<<<1, 256, 0, stream>>>(spec, allemb, HID);

    // ---- ontology GAT x2 per graph ----
    auto gat_layer = [&](const float* x, int M, const int* e, int E,
                         const float* W, const float* aws, const float* awd,
                         const float* b, float* hbuf, float* outbuf) {
        const int T = E + M;
        hipMemsetAsync(oCnt, 0, (size_t)M * 4, stream);
        csr_count<<<cdiv_i(T, 256), 256, 0, stream>>>(e + E, E, M, oCnt);
        scan_excl(oCnt, oOffs, M);
        hipMemsetAsync(oCur, 0, (size_t)M * 4, stream);
        csr_fill<<<cdiv_i(T, 256), 256, 0, stream>>>(e, e + E, E, M, oOffs, oCur, oSrcl);
        gemm128<<<cdiv_i(M, 128), 256, 0, stream>>>(x, W, hbuf, M);
        att_scores<<<cdiv_i(M, 4), 256, 0, stream>>>(hbuf, aws, awd, oAs, oAd, M);
        gat_agg<<<cdiv_i(M, 4), 256, 0, stream>>>(hbuf, oAs, oAd, oOffs, oSrcl, b, outbuf, M);
    };

    int row_off = 1;
    for (int i = 0; i < 3; ++i) {
        gat_layer(tabs[i], Ms[i], e1s[i], E1s[i], ontW[i], ontAs[i], ontAd[i], ontB[i], oH, oE);
        gat_layer(oE, Ms[i], e2s[i], E2s[i], ontW[i], ontAs[i], ontAd[i], ontB[i], oH, oE);
        gather_rows<<<cdiv_i((long)Ls[i] * 32, 256), 256, 0, stream>>>(
            oE, maps[i], allemb + (size_t)row_off * HID, Ls[i]);
        row_off += Ls[i];
    }

    // ---- patient sides: 3 GCN layers each ----
    auto run_side = [&](const int* xidx, const int* eg, const int* batch, float* fbuf) {
        const int T = EP + NP;
        hipMemsetAsync(pCnt, 0, (size_t)NP * 4, stream);
        csr_count<<<cdiv_i(T, 256), 256, 0, stream>>>(eg + EP, EP, NP, pCnt);
        scan_excl(pCnt, pOffs, NP);
        hipMemsetAsync(pCur, 0, (size_t)NP * 4, stream);
        csr_fill<<<cdiv_i(T, 256), 256, 0, stream>>>(eg, eg + EP, EP, NP, pOffs, pCur, pSrcl);
        deg_inv<<<cdiv_i(NP, 256), 256, 0, stream>>>(pCnt, dinv, NP);
        gather_rows<<<cdiv_i((long)NP * 32, 256), 256, 0, stream>>>(allemb, xidx, xbuf, NP);
        for (int l = 0; l < 3; ++l) {
            gemm128<<<cdiv_i(NP, 128), 256, 0, stream>>>(xbuf, gcnW[l], xw, NP);
            gcn_agg<<<cdiv_i(NP, 4), 256, 0, stream>>>(xw, dinv, pOffs, pSrcl, gcnB[l], xbuf, NP);
        }
        hipMemsetAsync(gcnt, 0, (size_t)B * 4, stream);
        csr_count<<<cdiv_i(NP, 256), 256, 0, stream>>>(batch, NP, 0, gcnt);
        scan_excl(gcnt, gstart, B);
        gather_rows<<<cdiv_i((long)B * 32, 256), 256, 0, stream>>>(xbuf, gstart, fbuf, B);
    };

    run_side(left_x, left_eg, left_batch, lf);
    run_side(right_x, right_eg, right_batch, rf);

    cosine_k<<<cdiv_i(B, 4), 256, 0, stream>>>(lf, rf, (float*)d_out, B);
}

// Round 3
// 864.727 us; speedup vs baseline: 1.6123x; 1.6123x over previous
//
#include <hip/hip_runtime.h>
#include <hip/hip_bf16.h>

#define HID 128

typedef unsigned int uint;
typedef unsigned short ushort;
typedef short short8 __attribute__((ext_vector_type(8)));
typedef float f32x4 __attribute__((ext_vector_type(4)));

static inline int cdiv_i(long a, long b) { return (int)((a + b - 1) / b); }

__device__ __forceinline__ float bf2f(uint hi) {
    return __builtin_bit_cast(float, hi << 16);
}
__device__ __forceinline__ ushort f2bf(float f) {  // RNE
    uint u = __builtin_bit_cast(uint, f);
    u = (u + 0x7fffu + ((u >> 16) & 1u)) >> 16;
    return (ushort)u;
}

// ---------------------------------------------------------------------------
// MFMA GEMM: C[M x 128] = A[M x 128] @ W[128 x 128] + bias, bf16 MFMA fp32 acc.
// Block 256 = 4 waves; wave handles 32 rows (2 m-tiles of 16x16x32).
// W staged once in LDS as Wt[n][k] bf16 (stride 136 for bank spread);
// A-fragments loaded straight from global (each element read exactly once).
// ---------------------------------------------------------------------------
template <typename AT, typename OT>
__global__ __launch_bounds__(256) void gemm_mfma(const AT* __restrict__ A,
                                                 const float* __restrict__ W,
                                                 const float* __restrict__ bias,
                                                 OT* __restrict__ C, int M) {
    __shared__ ushort wl[128 * 136];  // Wt[n][k], 34.8 KB
    const int tid = threadIdx.x;
#pragma unroll
    for (int rep = 0; rep < 16; ++rep) {
        const int idx = tid + 256 * rep;   // over 4096 float4 groups of W
        const int k = idx >> 5;            // W row (k)
        const int ng = idx & 31;           // n-group of 4
        const float4 w = ((const float4*)W)[idx];
        wl[(ng * 4 + 0) * 136 + k] = f2bf(w.x);
        wl[(ng * 4 + 1) * 136 + k] = f2bf(w.y);
        wl[(ng * 4 + 2) * 136 + k] = f2bf(w.z);
        wl[(ng * 4 + 3) * 136 + k] = f2bf(w.w);
    }
    __syncthreads();

    const int wave = tid >> 6, lane = tid & 63;
    const int r = lane & 15, q = lane >> 4;
    const long m0 = (long)blockIdx.x * 128 + wave * 32;

    f32x4 acc[2][8];
#pragma unroll
    for (int mi = 0; mi < 2; ++mi)
#pragma unroll
        for (int ni = 0; ni < 8; ++ni) acc[mi][ni] = (f32x4)0.f;

#pragma unroll
    for (int t = 0; t < 4; ++t) {  // k-step of 32
        const int koff = t * 32 + q * 8;
        short8 bfr[8];
#pragma unroll
        for (int ni = 0; ni < 8; ++ni) {
            const uint4 raw = *(const uint4*)(&wl[(ni * 16 + r) * 136 + koff]);
            bfr[ni] = __builtin_bit_cast(short8, raw);
        }
#pragma unroll
        for (int mi = 0; mi < 2; ++mi) {
            long row = m0 + mi * 16 + r;
            if (row >= M) row = M - 1;  // A always ws-backed; clamp for safety
            short8 af;
            if constexpr (__is_same(AT, ushort)) {
                const uint4 raw = *(const uint4*)(A + row * 128 + koff);
                af = __builtin_bit_cast(short8, raw);
            } else {
                const float4* p = (const float4*)(A + row * 128 + koff);
                const float4 x0 = p[0], x1 = p[1];
                af[0] = (short)f2bf(x0.x); af[1] = (short)f2bf(x0.y);
                af[2] = (short)f2bf(x0.z); af[3] = (short)f2bf(x0.w);
                af[4] = (short)f2bf(x1.x); af[5] = (short)f2bf(x1.y);
                af[6] = (short)f2bf(x1.z); af[7] = (short)f2bf(x1.w);
            }
#pragma unroll
            for (int ni = 0; ni < 8; ++ni)
                acc[mi][ni] = __builtin_amdgcn_mfma_f32_16x16x32_bf16(
                    af, bfr[ni], acc[mi][ni], 0, 0, 0);
        }
    }

    // epilogue: C/D layout col=lane&15, row=(lane>>4)*4+reg
#pragma unroll
    for (int mi = 0; mi < 2; ++mi) {
#pragma unroll
        for (int ni = 0; ni < 8; ++ni) {
            const int col = ni * 16 + r;
            const float bv = bias[col];
#pragma unroll
            for (int reg = 0; reg < 4; ++reg) {
                const long row = m0 + mi * 16 + q * 4 + reg;
                if (row < M) {
                    const float v = acc[mi][ni][reg] + bv;
                    if constexpr (__is_same(OT, ushort))
                        C[row * 128 + col] = f2bf(v);
                    else
                        C[row * 128 + col] = v;
                }
            }
        }
    }
}

// ---------------------------------------------------------------------------
// wa[0:128] = W @ asrc, wa[128:256] = W @ adst  (row dots, 1 block)
// ---------------------------------------------------------------------------
__global__ __launch_bounds__(256) void wvec_k(const float* __restrict__ W,
                                              const float* __restrict__ as,
                                              const float* __restrict__ ad,
                                              float* __restrict__ wa) {
    const int t = threadIdx.x;
    const int row = t & 127;
    const float* a = (t < 128) ? as : ad;
    const float4* wr = (const float4*)(W + row * 128);
    const float4* av = (const float4*)a;
    float s = 0.f;
#pragma unroll
    for (int i = 0; i < 32; ++i) {
        const float4 w = wr[i], x = av[i];
        s += w.x * x.x + w.y * x.y + w.z * x.z + w.w * x.w;
    }
    wa[t] = s;
}

// ---------------------------------------------------------------------------
// Attention scores directly from x: a_src = x.(W asrc), a_dst = x.(W adst)
// ---------------------------------------------------------------------------
__global__ __launch_bounds__(256) void att_scores(const float* __restrict__ x,
                                                  const float* __restrict__ wa,
                                                  float* __restrict__ as_o,
                                                  float* __restrict__ ad_o, int M) {
    const int node = blockIdx.x * 4 + (threadIdx.x >> 6);
    const int lane = threadIdx.x & 63;
    if (node >= M) return;
    const float h0 = x[(size_t)node * 128 + lane];
    const float h1 = x[(size_t)node * 128 + 64 + lane];
    float s = h0 * wa[lane] + h1 * wa[64 + lane];
    float d = h0 * wa[128 + lane] + h1 * wa[192 + lane];
#pragma unroll
    for (int o = 32; o > 0; o >>= 1) {
        s += __shfl_down(s, o);
        d += __shfl_down(d, o);
    }
    if (lane == 0) { as_o[node] = s; ad_o[node] = d; }
}

// ---------------------------------------------------------------------------
// Batched CSR build over 10 lists in one virtual node space.
// Lists 0-5: ontology e1/e2 (with self loops), 6-7: patient sides (loops),
// 8-9: batch histograms (no loops; offs slice gives first-node cumsum).
// ---------------------------------------------------------------------------
struct CsrDesc {
    const int* esrc[10];
    const int* edst[10];
    int ebase[11];
    int lbase[11];
    int nbase[10];
    int totE;
    int totL;
};

__global__ void csr_count_b(CsrDesc d, int* __restrict__ cnt) {
    const int i = blockIdx.x * 256 + threadIdx.x;
    if (i < d.totE) {
        int li = 0;
#pragma unroll
        for (int k = 1; k < 10; ++k) li += (i >= d.ebase[k]);
        atomicAdd(&cnt[d.nbase[li] + d.edst[li][i - d.ebase[li]]], 1);
    } else if (i < d.totE + d.totL) {
        const int k2 = i - d.totE;
        int li = 0;
#pragma unroll
        for (int k = 1; k < 10; ++k) li += (k2 >= d.lbase[k]);
        atomicAdd(&cnt[d.nbase[li] + (k2 - d.lbase[li])], 1);
    }
}

__global__ void csr_fill_b(CsrDesc d, const int* __restrict__ offs, int* cur,
                           int* __restrict__ srcl) {
    const int i = blockIdx.x * 256 + threadIdx.x;
    int v, s;
    if (i < d.totE) {
        int li = 0;
#pragma unroll
        for (int k = 1; k < 10; ++k) li += (i >= d.ebase[k]);
        const int j = i - d.ebase[li];
        v = d.nbase[li] + d.edst[li][j];
        s = d.esrc[li][j];
    } else if (i < d.totE + d.totL) {
        const int k2 = i - d.totE;
        int li = 0;
#pragma unroll
        for (int k = 1; k < 10; ++k) li += (k2 >= d.lbase[k]);
        const int j = k2 - d.lbase[li];
        v = d.nbase[li] + j;
        s = j;
    } else return;
    const int pos = atomicAdd(&cur[v], 1);
    srcl[offs[v] + pos] = s;
}

// ---------------------------------------------------------------------------
// 3-phase exclusive scan (int). out has n+1 entries.
// ---------------------------------------------------------------------------
__global__ __launch_bounds__(1024) void scan_tile(const int* __restrict__ in,
                                                  int* __restrict__ out,
                                                  int* __restrict__ bsum, int n) {
    __shared__ int buf[1024];
    const int tid = threadIdx.x;
    const int i = blockIdx.x * 1024 + tid;
    const int v = (i < n) ? in[i] : 0;
    buf[tid] = v;
    __syncthreads();
    int x = v;
    for (int o = 1; o < 1024; o <<= 1) {
        const int t = (tid >= o) ? buf[tid - o] : 0;
        __syncthreads();
        x += t;
        buf[tid] = x;
        __syncthreads();
    }
    if (i < n) out[i] = x - v;
    if (tid == 1023) bsum[blockIdx.x] = x;
}

__global__ __launch_bounds__(1024) void scan_single(int* __restrict__ bsum, int nb) {
    __shared__ int buf[1024];
    const int tid = threadIdx.x;
    const int v = (tid < nb) ? bsum[tid] : 0;
    buf[tid] = v;
    __syncthreads();
    int x = v;
    for (int o = 1; o < 1024; o <<= 1) {
        const int t = (tid >= o) ? buf[tid - o] : 0;
        __syncthreads();
        x += t;
        buf[tid] = x;
        __syncthreads();
    }
    if (tid < nb) bsum[tid] = x - v;
    if (tid == 1023) bsum[nb] = x;
}

__global__ void scan_add(int* __restrict__ out, const int* __restrict__ bsum,
                         int n, int nb) {
    const int i = blockIdx.x * 256 + threadIdx.x;
    if (i < n) out[i] += bsum[i >> 10];
    else if (i == n) out[i] = bsum[nb];
}

// ---------------------------------------------------------------------------
// GAT aggregation in x-space (pre-GEMM): y = softmax-weighted sum of x[src].
// fp32 in/out (ontology tables are small, L2-resident). No bias here.
// ---------------------------------------------------------------------------
__global__ __launch_bounds__(256) void gat_agg(const float* __restrict__ x,
                                               const float* __restrict__ av_s,
                                               const float* __restrict__ av_d,
                                               const int* __restrict__ offs,
                                               const int* __restrict__ srcl,
                                               float* __restrict__ y, int M) {
    const int node = blockIdx.x * 4 + (threadIdx.x >> 6);
    const int lane = threadIdx.x & 63;
    if (node >= M) return;
    const int beg = offs[node], end = offs[node + 1];
    const float adv = av_d[node];
    float m = -1e30f;
    for (int j = beg; j < end; ++j) {
        float e = av_s[srcl[j]] + adv;
        e = (e > 0.f) ? e : 0.2f * e;
        m = fmaxf(m, e);
    }
    float denom = 0.f, a0 = 0.f, a1 = 0.f;
    int j = beg;
    for (; j + 4 <= end; j += 4) {
        const int s0 = srcl[j], s1 = srcl[j + 1], s2 = srcl[j + 2], s3 = srcl[j + 3];
        float e0 = av_s[s0] + adv; e0 = (e0 > 0.f) ? e0 : 0.2f * e0;
        float e1 = av_s[s1] + adv; e1 = (e1 > 0.f) ? e1 : 0.2f * e1;
        float e2 = av_s[s2] + adv; e2 = (e2 > 0.f) ? e2 : 0.2f * e2;
        float e3 = av_s[s3] + adv; e3 = (e3 > 0.f) ? e3 : 0.2f * e3;
        const float w0 = __expf(e0 - m), w1 = __expf(e1 - m);
        const float w2 = __expf(e2 - m), w3 = __expf(e3 - m);
        const float2 h0 = *(const float2*)(x + (size_t)s0 * 128 + lane * 2);
        const float2 h1 = *(const float2*)(x + (size_t)s1 * 128 + lane * 2);
        const float2 h2 = *(const float2*)(x + (size_t)s2 * 128 + lane * 2);
        const float2 h3 = *(const float2*)(x + (size_t)s3 * 128 + lane * 2);
        denom += w0 + w1 + w2 + w3;
        a0 += w0 * h0.x + w1 * h1.x + w2 * h2.x + w3 * h3.x;
        a1 += w0 * h0.y + w1 * h1.y + w2 * h2.y + w3 * h3.y;
    }
    for (; j < end; ++j) {
        const int s = srcl[j];
        float e = av_s[s] + adv;
        e = (e > 0.f) ? e : 0.2f * e;
        const float w = __expf(e - m);
        denom += w;
        const float2 hv = *(const float2*)(x + (size_t)s * 128 + lane * 2);
        a0 += w * hv.x;
        a1 += w * hv.y;
    }
    const float inv = 1.f / denom;
    *(float2*)(y + (size_t)node * 128 + lane * 2) = make_float2(a0 * inv, a1 * inv);
}

// ---------------------------------------------------------------------------
// GCN aggregation, bf16 features, fp32 accumulate, 4-wide edge unroll.
// ---------------------------------------------------------------------------
__device__ __forceinline__ void gcn_node_acc(const ushort* __restrict__ x,
                                             const float* __restrict__ dinv,
                                             const int* __restrict__ srcl,
                                             int beg, int end, float dv, int lane,
                                             float& a0, float& a1) {
    int j = beg;
    for (; j + 4 <= end; j += 4) {
        const int s0 = srcl[j], s1 = srcl[j + 1], s2 = srcl[j + 2], s3 = srcl[j + 3];
        const float n0 = dv * dinv[s0], n1 = dv * dinv[s1];
        const float n2 = dv * dinv[s2], n3 = dv * dinv[s3];
        const uint v0 = *(const uint*)(x + (size_t)s0 * 128 + lane * 2);
        const uint v1 = *(const uint*)(x + (size_t)s1 * 128 + lane * 2);
        const uint v2 = *(const uint*)(x + (size_t)s2 * 128 + lane * 2);
        const uint v3 = *(const uint*)(x + (size_t)s3 * 128 + lane * 2);
        a0 += n0 * bf2f(v0 & 0xffff) + n1 * bf2f(v1 & 0xffff) +
              n2 * bf2f(v2 & 0xffff) + n3 * bf2f(v3 & 0xffff);
        a1 += n0 * bf2f(v0 >> 16) + n1 * bf2f(v1 >> 16) +
              n2 * bf2f(v2 >> 16) + n3 * bf2f(v3 >> 16);
    }
    for (; j < end; ++j) {
        const int s = srcl[j];
        const float nw = dv * dinv[s];
        const uint v = *(const uint*)(x + (size_t)s * 128 + lane * 2);
        a0 += nw * bf2f(v & 0xffff);
        a1 += nw * bf2f(v >> 16);
    }
}

__global__ __launch_bounds__(256) void gcn_agg_b(const ushort* __restrict__ x,
                                                 const float* __restrict__ dinv,
                                                 const int* __restrict__ offs,
                                                 const int* __restrict__ srcl,
                                                 ushort* __restrict__ y, int M) {
    const int node = blockIdx.x * 4 + (threadIdx.x >> 6);
    const int lane = threadIdx.x & 63;
    if (node >= M) return;
    const int beg = offs[node], end = offs[node + 1];
    const float dv = dinv[node];
    float a0 = 0.f, a1 = 0.f;
    gcn_node_acc(x, dinv, srcl, beg, end, dv, lane, a0, a1);
    *(uint*)(y + (size_t)node * 128 + lane * 2) =
        (uint)f2bf(a0) | ((uint)f2bf(a1) << 16);
}

// Last GCN layer: aggregate only the first node of each graph (offs_b slice
// of the batched scan IS the first-node cumsum).
__global__ __launch_bounds__(256) void gcn_agg_final(const ushort* __restrict__ x,
                                                     const float* __restrict__ dinv,
                                                     const int* __restrict__ offs,
                                                     const int* __restrict__ srcl,
                                                     const int* __restrict__ offs_b,
                                                     ushort* __restrict__ y, int B) {
    const int g = blockIdx.x * 4 + (threadIdx.x >> 6);
    const int lane = threadIdx.x & 63;
    if (g >= B) return;
    const int node = offs_b[g] - offs_b[0];
    const int beg = offs[node], end = offs[node + 1];
    const float dv = dinv[node];
    float a0 = 0.f, a1 = 0.f;
    gcn_node_acc(x, dinv, srcl, beg, end, dv, lane, a0, a1);
    *(uint*)(y + (size_t)g * 128 + lane * 2) =
        (uint)f2bf(a0) | ((uint)f2bf(a1) << 16);
}

__global__ void deg_inv(const int* __restrict__ cnt, float* __restrict__ dinv, int M) {
    const int i = blockIdx.x * 256 + threadIdx.x;
    if (i < M) dinv[i] = rsqrtf(fmaxf((float)cnt[i], 1e-12f));
}

// ---------------------------------------------------------------------------
// Gathers
// ---------------------------------------------------------------------------
__global__ void gather_rows(const float* __restrict__ tab, const int* __restrict__ idx,
                            float* __restrict__ out, int n) {
    const long t = (long)blockIdx.x * 256 + threadIdx.x;
    if (t >= (long)n * 32) return;
    const int row = (int)(t >> 5);
    const int c = (int)(t & 31);
    const int srow = idx[row];
    ((float4*)out)[(long)row * 32 + c] = ((const float4*)tab)[(long)srow * 32 + c];
}

__global__ void gather_rows_b(const float* __restrict__ tab, const int* __restrict__ idx,
                              ushort* __restrict__ out, int n) {
    const long t = (long)blockIdx.x * 256 + threadIdx.x;
    if (t >= (long)n * 32) return;
    const int row = (int)(t >> 5);
    const int c = (int)(t & 31);
    const int srow = idx[row];
    const float4 v = ((const float4*)tab)[(long)srow * 32 + c];
    const uint lo = (uint)f2bf(v.x) | ((uint)f2bf(v.y) << 16);
    const uint hi = (uint)f2bf(v.z) | ((uint)f2bf(v.w) << 16);
    *(uint2*)(out + (long)row * 128 + c * 4) = make_uint2(lo, hi);
}

__global__ void copy_vec(const float* __restrict__ src, float* __restrict__ dst, int n) {
    const int i = blockIdx.x * 256 + threadIdx.x;
    if (i < n) dst[i] = src[i];
}

// ---------------------------------------------------------------------------
// Cosine similarity: 1 wave/graph
// ---------------------------------------------------------------------------
__global__ __launch_bounds__(256) void cosine_k(const float* __restrict__ lf,
                                                const float* __restrict__ rf,
                                                float* __restrict__ out, int B) {
    const int g = blockIdx.x * 4 + (threadIdx.x >> 6);
    const int lane = threadIdx.x & 63;
    if (g >= B) return;
    const float2 a = *(const float2*)(lf + (size_t)g * 128 + lane * 2);
    const float2 b = *(const float2*)(rf + (size_t)g * 128 + lane * 2);
    float num = a.x * b.x + a.y * b.y;
    float na = a.x * a.x + a.y * a.y;
    float nb = b.x * b.x + b.y * b.y;
#pragma unroll
    for (int o = 32; o > 0; o >>= 1) {
        num += __shfl_down(num, o);
        na += __shfl_down(na, o);
        nb += __shfl_down(nb, o);
    }
    if (lane == 0)
        out[g] = num / (fmaxf(sqrtf(na), 1e-6f) * fmaxf(sqrtf(nb), 1e-6f));
}

// ---------------------------------------------------------------------------
extern "C" void kernel_launch(void* const* d_in, const int* in_sizes, int n_in,
                              void* d_out, int out_size, void* d_ws, size_t ws_size,
                              hipStream_t stream) {
    (void)n_in; (void)ws_size;
    // setup_inputs() dict order
    const float* spec = (const float*)d_in[0];
    const float* tabs[3] = {(const float*)d_in[1], (const float*)d_in[2], (const float*)d_in[3]};
    const float* ontW[3] = {(const float*)d_in[4], (const float*)d_in[8], (const float*)d_in[12]};
    const float* ontAs[3] = {(const float*)d_in[5], (const float*)d_in[9], (const float*)d_in[13]};
    const float* ontAd[3] = {(const float*)d_in[6], (const float*)d_in[10], (const float*)d_in[14]};
    const float* ontB[3] = {(const float*)d_in[7], (const float*)d_in[11], (const float*)d_in[15]};
    const float* gcnW[3] = {(const float*)d_in[16], (const float*)d_in[18], (const float*)d_in[20]};
    const float* gcnB[3] = {(const float*)d_in[17], (const float*)d_in[19], (const float*)d_in[21]};
    const int* e1s[3] = {(const int*)d_in[22], (const int*)d_in[24], (const int*)d_in[26]};
    const int* e2s[3] = {(const int*)d_in[23], (const int*)d_in[25], (const int*)d_in[27]};
    const int* maps[3] = {(const int*)d_in[28], (const int*)d_in[29], (const int*)d_in[30]};
    const int* left_x = (const int*)d_in[31];
    const int* right_x = (const int*)d_in[32];
    const int* left_eg = (const int*)d_in[33];
    const int* right_eg = (const int*)d_in[34];
    const int* left_batch = (const int*)d_in[35];
    const int* right_batch = (const int*)d_in[36];

    int Ms[3] = {in_sizes[1] / HID, in_sizes[2] / HID, in_sizes[3] / HID};
    int E1s[3] = {in_sizes[22] / 2, in_sizes[24] / 2, in_sizes[26] / 2};
    int E2s[3] = {in_sizes[23] / 2, in_sizes[25] / 2, in_sizes[27] / 2};
    int Ls[3] = {in_sizes[28], in_sizes[29], in_sizes[30]};
    const int NP = in_sizes[31];
    const int EP = in_sizes[33] / 2;
    const int B = out_size;
    const int ALL = 1 + Ls[0] + Ls[1] + Ls[2];

    int maxM = 0;
    for (int i = 0; i < 3; ++i) if (Ms[i] > maxM) maxM = Ms[i];

    // ---- batched CSR descriptor: 10 lists in one virtual node space ----
    CsrDesc dsc;
    int eCnt[10], lCnt[10], nCnt[10];
    for (int i = 0; i < 3; ++i) {
        dsc.esrc[2 * i] = e1s[i];     dsc.edst[2 * i] = e1s[i] + E1s[i];
        dsc.esrc[2 * i + 1] = e2s[i]; dsc.edst[2 * i + 1] = e2s[i] + E2s[i];
        eCnt[2 * i] = E1s[i]; eCnt[2 * i + 1] = E2s[i];
        lCnt[2 * i] = Ms[i];  lCnt[2 * i + 1] = Ms[i];
        nCnt[2 * i] = Ms[i];  nCnt[2 * i + 1] = Ms[i];
    }
    dsc.esrc[6] = left_eg;  dsc.edst[6] = left_eg + EP;  eCnt[6] = EP; lCnt[6] = NP; nCnt[6] = NP;
    dsc.esrc[7] = right_eg; dsc.edst[7] = right_eg + EP; eCnt[7] = EP; lCnt[7] = NP; nCnt[7] = NP;
    dsc.esrc[8] = left_batch;  dsc.edst[8] = left_batch;  eCnt[8] = NP; lCnt[8] = 0; nCnt[8] = B;
    dsc.esrc[9] = right_batch; dsc.edst[9] = right_batch; eCnt[9] = NP; lCnt[9] = 0; nCnt[9] = B;
    dsc.ebase[0] = dsc.lbase[0] = 0;
    int nb_acc = 0;
    for (int i = 0; i < 10; ++i) {
        dsc.ebase[i + 1] = dsc.ebase[i] + eCnt[i];
        dsc.lbase[i + 1] = dsc.lbase[i] + lCnt[i];
        dsc.nbase[i] = nb_acc;
        nb_acc += nCnt[i];
    }
    const int NV = nb_acc;
    dsc.totE = dsc.ebase[10];
    dsc.totL = dsc.lbase[10];
    const int totEntries = dsc.totE + dsc.totL;

    // ---- workspace layout ----
    char* ws = (char*)d_ws;
    size_t off = 0;
    auto alloc = [&](size_t bytes) -> void* {
        off = (off + 255) & ~(size_t)255;
        void* p = ws + off;
        off += bytes;
        return p;
    };
    float* allemb = (float*)alloc((size_t)ALL * HID * 4);
    float* lf = (float*)alloc((size_t)B * HID * 4);
    float* rf = (float*)alloc((size_t)B * HID * 4);
    int* cnt = (int*)alloc((size_t)NV * 4);
    int* cur = (int*)alloc((size_t)NV * 4);
    int* offs = (int*)alloc((size_t)(NV + 1) * 4);
    int* srcl = (int*)alloc((size_t)totEntries * 4);
    int* bsum = (int*)alloc(1025 * 4);
    float* dinv = (float*)alloc((size_t)2 * NP * 4);
    float* yo = (float*)alloc((size_t)maxM * HID * 4);
    float* oE = (float*)alloc((size_t)maxM * HID * 4);
    float* oAs = (float*)alloc((size_t)maxM * 4);
    float* oAd = (float*)alloc((size_t)maxM * 4);
    float* wa = (float*)alloc(256 * 4);
    ushort* xb = (ushort*)alloc((size_t)NP * HID * 2);
    ushort* yb = (ushort*)alloc((size_t)NP * HID * 2);
    ushort* y3 = (ushort*)alloc((size_t)B * HID * 2);

    auto scan_excl = [&](const int* in, int* out, int n) {
        const int nb = cdiv_i(n, 1024);
        scan_tile<<<nb, 1024, 0, stream>>>(in, out, bsum, n);
        scan_single<<<1, 1024, 0, stream>>>(bsum, nb);
        scan_add<<<cdiv_i(n + 1, 256), 256, 0, stream>>>(out, bsum, n, nb);
    };

    // ---- CSR build (topology only; once) ----
    hipMemsetAsync(cnt, 0, (size_t)NV * 4, stream);
    csr_count_b<<<cdiv_i(totEntries, 256), 256, 0, stream>>>(dsc, cnt);
    scan_excl(cnt, offs, NV);
    hipMemsetAsync(cur, 0, (size_t)NV * 4, stream);
    csr_fill_b<<<cdiv_i(totEntries, 256), 256, 0, stream>>>(dsc, offs, cur, srcl);
    deg_inv<<<cdiv_i(2 * NP, 256), 256, 0, stream>>>(cnt + dsc.nbase[6], dinv, 2 * NP);

    copy_vec<<<1, 256, 0, stream>>>(spec, allemb, HID);

    // ---- ontology: 2 GAT layers per graph ----
    int row_off = 1;
    for (int i = 0; i < 3; ++i) {
        const int M = Ms[i];
        wvec_k<<<1, 256, 0, stream>>>(ontW[i], ontAs[i], ontAd[i], wa);
        // layer 1 (edges e1): input = table
        att_scores<<<cdiv_i(M, 4), 256, 0, stream>>>(tabs[i], wa, oAs, oAd, M);
        gat_agg<<<cdiv_i(M, 4), 256, 0, stream>>>(tabs[i], oAs, oAd,
                                                  offs + dsc.nbase[2 * i], srcl, yo, M);
        gemm_mfma<float, float><<<cdiv_i(M, 128), 256, 0, stream>>>(yo, ontW[i], ontB[i], oE, M);
        // layer 2 (edges e2): input = oE
        att_scores<<<cdiv_i(M, 4), 256, 0, stream>>>(oE, wa, oAs, oAd, M);
        gat_agg<<<cdiv_i(M, 4), 256, 0, stream>>>(oE, oAs, oAd,
                                                  offs + dsc.nbase[2 * i + 1], srcl, yo, M);
        gemm_mfma<float, float><<<cdiv_i(M, 128), 256, 0, stream>>>(yo, ontW[i], ontB[i], oE, M);
        gather_rows<<<cdiv_i((long)Ls[i] * 32, 256), 256, 0, stream>>>(
            oE, maps[i], allemb + (size_t)row_off * HID, Ls[i]);
        row_off += Ls[i];
    }

    // ---- patient sides: agg-first GCN; layer 3 only at final nodes ----
    auto run_side = [&](const int* xidx, int plist, int blist, const float* dv, float* fbuf) {
        const int* poffs = offs + dsc.nbase[plist];
        const int* boffs = offs + dsc.nbase[blist];
        gather_rows_b<<<cdiv_i((long)NP * 32, 256), 256, 0, stream>>>(allemb, xidx, xb, NP);
        for (int l = 0; l < 2; ++l) {
            gcn_agg_b<<<cdiv_i(NP, 4), 256, 0, stream>>>(xb, dv, poffs, srcl, yb, NP);
            gemm_mfma<ushort, ushort><<<cdiv_i(NP, 128), 256, 0, stream>>>(yb, gcnW[l], gcnB[l], xb, NP);
        }
        gcn_agg_final<<<cdiv_i(B, 4), 256, 0, stream>>>(xb, dv, poffs, srcl, boffs, y3, B);
        gemm_mfma<ushort, float><<<cdiv_i(B, 128), 256, 0, stream>>>(y3, gcnW[2], gcnB[2], fbuf, B);
    };

    run_side(left_x, 6, 8, dinv, lf);
    run_side(right_x, 7, 9, dinv + NP, rf);

    cosine_k<<<cdiv_i(B, 4), 256, 0, stream>>>(lf, rf, (float*)d_out, B);
}

// Round 4
// 647.963 us; speedup vs baseline: 2.1516x; 1.3345x over previous
//
#include <hip/hip_runtime.h>
#include <hip/hip_bf16.h>

#define HID 128

typedef unsigned int uint;
typedef unsigned short ushort;
typedef short short8 __attribute__((ext_vector_type(8)));
typedef float f32x4 __attribute__((ext_vector_type(4)));

static inline int cdiv_i(long a, long b) { return (int)((a + b - 1) / b); }

__device__ __forceinline__ float bf2f(uint hi) {
    return __builtin_bit_cast(float, hi << 16);
}
__device__ __forceinline__ ushort f2bf(float f) {  // RNE
    uint u = __builtin_bit_cast(uint, f);
    u = (u + 0x7fffu + ((u >> 16) & 1u)) >> 16;
    return (ushort)u;
}

// ---------------------------------------------------------------------------
// Shared MFMA GEMM machinery: C[rows x 128] = A_bf16[rows x 128] @ W + bias.
// W staged in LDS as Wt[n][k] bf16 (stride 136); block = 4 waves x 32 rows.
// ---------------------------------------------------------------------------
__device__ __forceinline__ void stage_w(const float* __restrict__ W,
                                        ushort* __restrict__ wl) {
    const int tid = threadIdx.x;
#pragma unroll
    for (int rep = 0; rep < 16; ++rep) {
        const int idx = tid + 256 * rep;
        const int k = idx >> 5;
        const int ng = idx & 31;
        const float4 w = ((const float4*)W)[idx];
        wl[(ng * 4 + 0) * 136 + k] = f2bf(w.x);
        wl[(ng * 4 + 1) * 136 + k] = f2bf(w.y);
        wl[(ng * 4 + 2) * 136 + k] = f2bf(w.z);
        wl[(ng * 4 + 3) * 136 + k] = f2bf(w.w);
    }
}

template <typename OT>
__device__ __forceinline__ void mfma_tile(const ushort* __restrict__ A,
                                          const ushort* __restrict__ wl,
                                          const float* __restrict__ bias,
                                          OT* __restrict__ C,
                                          long m0blk, long rowEnd) {
    const int tid = threadIdx.x;
    const int wave = tid >> 6, lane = tid & 63;
    const int r = lane & 15, q = lane >> 4;
    const long m0 = m0blk + wave * 32;

    f32x4 acc[2][8];
#pragma unroll
    for (int mi = 0; mi < 2; ++mi)
#pragma unroll
        for (int ni = 0; ni < 8; ++ni) acc[mi][ni] = (f32x4)0.f;

#pragma unroll
    for (int t = 0; t < 4; ++t) {
        const int koff = t * 32 + q * 8;
        short8 bfr[8];
#pragma unroll
        for (int ni = 0; ni < 8; ++ni) {
            const uint4 raw = *(const uint4*)(&wl[(ni * 16 + r) * 136 + koff]);
            bfr[ni] = __builtin_bit_cast(short8, raw);
        }
#pragma unroll
        for (int mi = 0; mi < 2; ++mi) {
            long row = m0 + mi * 16 + r;
            if (row >= rowEnd) row = rowEnd - 1;
            const uint4 raw = *(const uint4*)(A + row * 128 + koff);
            const short8 af = __builtin_bit_cast(short8, raw);
#pragma unroll
            for (int ni = 0; ni < 8; ++ni)
                acc[mi][ni] = __builtin_amdgcn_mfma_f32_16x16x32_bf16(
                    af, bfr[ni], acc[mi][ni], 0, 0, 0);
        }
    }

#pragma unroll
    for (int mi = 0; mi < 2; ++mi) {
#pragma unroll
        for (int ni = 0; ni < 8; ++ni) {
            const int col = ni * 16 + r;
            const float bv = bias[col];
#pragma unroll
            for (int reg = 0; reg < 4; ++reg) {
                const long row = m0 + mi * 16 + q * 4 + reg;
                if (row < rowEnd) {
                    const float v = acc[mi][ni][reg] + bv;
                    if constexpr (__is_same(OT, ushort))
                        C[row * 128 + col] = f2bf(v);
                    else
                        C[row * 128 + col] = v;
                }
            }
        }
    }
}

template <typename OT>
__global__ __launch_bounds__(256) void gemm_gcn(const ushort* __restrict__ A,
                                                const float* __restrict__ W,
                                                const float* __restrict__ bias,
                                                OT* __restrict__ C, int M) {
    __shared__ ushort wl[128 * 136];
    stage_w(W, wl);
    __syncthreads();
    mfma_tile<OT>(A, wl, bias, C, (long)blockIdx.x * 128, M);
}

struct GOnto {
    const float* W0; const float* W1; const float* W2;
    const float* b0; const float* b1; const float* b2;
    int bs1, bs2;        // block-range starts of graphs 1,2
    int r1, r2, r3;      // row bases of graphs 1,2 and total rows
};

__global__ __launch_bounds__(256) void gemm_onto(const ushort* __restrict__ A,
                                                 GOnto g, float* __restrict__ C) {
    __shared__ ushort wl[128 * 136];
    const int b = blockIdx.x;
    const int gid = (b >= g.bs1) + (b >= g.bs2);
    const float* W = (gid == 0) ? g.W0 : (gid == 1) ? g.W1 : g.W2;
    const float* bi = (gid == 0) ? g.b0 : (gid == 1) ? g.b1 : g.b2;
    const int bloc = b - ((gid == 0) ? 0 : (gid == 1) ? g.bs1 : g.bs2);
    const long rb = (gid == 0) ? 0 : (gid == 1) ? g.r1 : g.r2;
    const long re = (gid == 0) ? g.r1 : (gid == 1) ? g.r2 : g.r3;
    stage_w(W, wl);
    __syncthreads();
    mfma_tile<float>(A, wl, bi, C, rb + (long)bloc * 128, re);
}

// ---------------------------------------------------------------------------
// Ontology: batched over 3 graphs in one combined node space.
// ---------------------------------------------------------------------------
struct P3 { const float* a; const float* b; const float* c; };

__global__ __launch_bounds__(256) void wvec_all(P3 Ws, P3 vs, P3 vd,
                                                float* __restrict__ wa) {
    const int g = blockIdx.x;
    const float* W = (g == 0) ? Ws.a : (g == 1) ? Ws.b : Ws.c;
    const float* s = (g == 0) ? vs.a : (g == 1) ? vs.b : vs.c;
    const float* d = (g == 0) ? vd.a : (g == 1) ? vd.b : vd.c;
    const int t = threadIdx.x;
    const int row = t & 127;
    const float* a = (t < 128) ? s : d;
    const float4* wr = (const float4*)(W + row * 128);
    const float4* av = (const float4*)a;
    float acc = 0.f;
#pragma unroll
    for (int i = 0; i < 32; ++i) {
        const float4 w = wr[i], x = av[i];
        acc += w.x * x.x + w.y * x.y + w.z * x.z + w.w * x.w;
    }
    wa[g * 256 + t] = acc;
}

struct OntoX { const float* x0; const float* x1; const float* x2; int r1, r2; };

__global__ __launch_bounds__(256) void att_all(OntoX ox, const float* __restrict__ wa,
                                               float* __restrict__ as_o,
                                               float* __restrict__ ad_o, int Mtot) {
    const int node = blockIdx.x * 4 + (threadIdx.x >> 6);
    const int lane = threadIdx.x & 63;
    if (node >= Mtot) return;
    const int gid = (node >= ox.r1) + (node >= ox.r2);
    const float* x = (gid == 0) ? ox.x0 : (gid == 1) ? ox.x1 : ox.x2;
    const int rb = (gid == 0) ? 0 : (gid == 1) ? ox.r1 : ox.r2;
    const float* row = x + (size_t)(node - rb) * 128;
    const float* w = wa + gid * 256;
    const float h0 = row[lane], h1 = row[64 + lane];
    float s = h0 * w[lane] + h1 * w[64 + lane];
    float d = h0 * w[128 + lane] + h1 * w[192 + lane];
#pragma unroll
    for (int o = 32; o > 0; o >>= 1) {
        s += __shfl_down(s, o);
        d += __shfl_down(d, o);
    }
    if (lane == 0) { as_o[node] = s; ad_o[node] = d; }
}

struct OntoG { int ob0, ob1, ob2; };

__global__ __launch_bounds__(256) void gat_all(OntoX ox, const float* __restrict__ as,
                                               const float* __restrict__ ad,
                                               const int* __restrict__ offs,
                                               const int* __restrict__ srcl, OntoG og,
                                               ushort* __restrict__ y, int Mtot) {
    const int node = blockIdx.x * 4 + (threadIdx.x >> 6);
    const int lane = threadIdx.x & 63;
    if (node >= Mtot) return;
    const int gid = (node >= ox.r1) + (node >= ox.r2);
    const float* x = (gid == 0) ? ox.x0 : (gid == 1) ? ox.x1 : ox.x2;
    const int rb = (gid == 0) ? 0 : (gid == 1) ? ox.r1 : ox.r2;
    const int ob = (gid == 0) ? og.ob0 : (gid == 1) ? og.ob1 : og.ob2;
    const int local = node - rb;
    const int beg = offs[ob + local], end = offs[ob + local + 1];
    const float adv = ad[node];
    float m = -1e30f;
    for (int j = beg; j < end; ++j) {
        float e = as[rb + srcl[j]] + adv;
        e = (e > 0.f) ? e : 0.2f * e;
        m = fmaxf(m, e);
    }
    float denom = 0.f, a0 = 0.f, a1 = 0.f;
    for (int j = beg; j < end; ++j) {
        const int s = srcl[j];
        float e = as[rb + s] + adv;
        e = (e > 0.f) ? e : 0.2f * e;
        const float w = __expf(e - m);
        denom += w;
        const float2 hv = *(const float2*)(x + (size_t)s * 128 + lane * 2);
        a0 += w * hv.x;
        a1 += w * hv.y;
    }
    const float inv = 1.f / denom;
    *(uint*)(y + (size_t)node * 128 + lane * 2) =
        (uint)f2bf(a0 * inv) | ((uint)f2bf(a1 * inv) << 16);
}

// ---------------------------------------------------------------------------
// Batched CSR build over 10 lists in one virtual node space.
// count records each entry's intra-dst position (atomic return) into pos[];
// fill is then atomic-free.
// ---------------------------------------------------------------------------
struct CsrDesc {
    const int* esrc[10];
    const int* edst[10];
    int ebase[11];
    int lbase[11];
    int nbase[10];
    int totE;
    int totL;
};

__global__ void csr_count_b(CsrDesc d, int* __restrict__ cnt, int* __restrict__ pos) {
    const int i = blockIdx.x * 256 + threadIdx.x;
    int v;
    if (i < d.totE) {
        int li = 0;
#pragma unroll
        for (int k = 1; k < 10; ++k) li += (i >= d.ebase[k]);
        v = d.nbase[li] + d.edst[li][i - d.ebase[li]];
    } else if (i < d.totE + d.totL) {
        const int k2 = i - d.totE;
        int li = 0;
#pragma unroll
        for (int k = 1; k < 10; ++k) li += (k2 >= d.lbase[k]);
        v = d.nbase[li] + (k2 - d.lbase[li]);
    } else return;
    pos[i] = atomicAdd(&cnt[v], 1);
}

__global__ void csr_fill_b(CsrDesc d, const int* __restrict__ offs,
                           const int* __restrict__ pos, int* __restrict__ srcl) {
    const int i = blockIdx.x * 256 + threadIdx.x;
    int v, s;
    if (i < d.totE) {
        int li = 0;
#pragma unroll
        for (int k = 1; k < 10; ++k) li += (i >= d.ebase[k]);
        const int j = i - d.ebase[li];
        v = d.nbase[li] + d.edst[li][j];
        s = d.esrc[li][j];
    } else if (i < d.totE + d.totL) {
        const int k2 = i - d.totE;
        int li = 0;
#pragma unroll
        for (int k = 1; k < 10; ++k) li += (k2 >= d.lbase[k]);
        const int j = k2 - d.lbase[li];
        v = d.nbase[li] + j;
        s = j;
    } else return;
    srcl[offs[v] + pos[i]] = s;
}

// ---------------------------------------------------------------------------
// 3-phase exclusive scan (int). out has n+1 entries.
// ---------------------------------------------------------------------------
__global__ __launch_bounds__(1024) void scan_tile(const int* __restrict__ in,
                                                  int* __restrict__ out,
                                                  int* __restrict__ bsum, int n) {
    __shared__ int buf[1024];
    const int tid = threadIdx.x;
    const int i = blockIdx.x * 1024 + tid;
    const int v = (i < n) ? in[i] : 0;
    buf[tid] = v;
    __syncthreads();
    int x = v;
    for (int o = 1; o < 1024; o <<= 1) {
        const int t = (tid >= o) ? buf[tid - o] : 0;
        __syncthreads();
        x += t;
        buf[tid] = x;
        __syncthreads();
    }
    if (i < n) out[i] = x - v;
    if (tid == 1023) bsum[blockIdx.x] = x;
}

__global__ __launch_bounds__(1024) void scan_single(int* __restrict__ bsum, int nb) {
    __shared__ int buf[1024];
    const int tid = threadIdx.x;
    const int v = (tid < nb) ? bsum[tid] : 0;
    buf[tid] = v;
    __syncthreads();
    int x = v;
    for (int o = 1; o < 1024; o <<= 1) {
        const int t = (tid >= o) ? buf[tid - o] : 0;
        __syncthreads();
        x += t;
        buf[tid] = x;
        __syncthreads();
    }
    if (tid < nb) bsum[tid] = x - v;
    if (tid == 1023) bsum[nb] = x;
}

__global__ void scan_add(int* __restrict__ out, const int* __restrict__ bsum,
                         int n, int nb) {
    const int i = blockIdx.x * 256 + threadIdx.x;
    if (i < n) out[i] += bsum[i >> 10];
    else if (i == n) out[i] = bsum[nb];
}

__global__ void deg_inv(const int* __restrict__ cnt, float* __restrict__ dinv, int M) {
    const int i = blockIdx.x * 256 + threadIdx.x;
    if (i < M) dinv[i] = rsqrtf(fmaxf((float)cnt[i], 1e-12f));
}

// ---------------------------------------------------------------------------
// allemb (bf16): row 0 = spec, then the 3 ontology maps out of combined oE.
// ---------------------------------------------------------------------------
struct EmbD {
    const float* spec; const float* oE;
    const int* m0; const int* m1; const int* m2;
    int lb2, lb3;  // 1+L0, 1+L0+L1
    int r1, r2;    // oE row bases of graphs 1,2
    long ALLr;
};

__global__ void build_emb(EmbD d, ushort* __restrict__ out) {
    const long t = (long)blockIdx.x * 256 + threadIdx.x;
    if (t >= d.ALLr * 16) return;
    const int row = (int)(t >> 4), c = (int)(t & 15);
    const float* src;
    if (row == 0) {
        src = d.spec;
    } else {
        const int seg = (row >= d.lb2) + (row >= d.lb3);
        const int local = row - ((seg == 0) ? 1 : (seg == 1) ? d.lb2 : d.lb3);
        const int* mp = (seg == 0) ? d.m0 : (seg == 1) ? d.m1 : d.m2;
        const int rb = (seg == 0) ? 0 : (seg == 1) ? d.r1 : d.r2;
        src = d.oE + (size_t)(rb + mp[local]) * 128;
    }
    const float4 f0 = ((const float4*)src)[c * 2];
    const float4 f1 = ((const float4*)src)[c * 2 + 1];
    uint4 o;
    o.x = (uint)f2bf(f0.x) | ((uint)f2bf(f0.y) << 16);
    o.y = (uint)f2bf(f0.z) | ((uint)f2bf(f0.w) << 16);
    o.z = (uint)f2bf(f1.x) | ((uint)f2bf(f1.y) << 16);
    o.w = (uint)f2bf(f1.z) | ((uint)f2bf(f1.w) << 16);
    *(uint4*)(out + (size_t)row * 128 + c * 8) = o;
}

// ---------------------------------------------------------------------------
// GCN aggregation (both sides fused; bf16 features, fp32 accumulate).
// Layer 1 reads allemb through the node-index array (fused gather).
// ---------------------------------------------------------------------------
__global__ __launch_bounds__(256) void gcn_agg1(const ushort* __restrict__ emb,
                                                const int* __restrict__ lx,
                                                const int* __restrict__ rx,
                                                const float* __restrict__ dinv,
                                                const int* __restrict__ offs6,
                                                const int* __restrict__ srcl,
                                                ushort* __restrict__ y, int NP) {
    const int n2 = blockIdx.x * 4 + (threadIdx.x >> 6);
    const int lane = threadIdx.x & 63;
    if (n2 >= 2 * NP) return;
    const int side = n2 >= NP;
    const int* xi = side ? rx : lx;
    const int sb = side ? NP : 0;
    const int beg = offs6[n2], end = offs6[n2 + 1];
    const float dv = dinv[n2];
    float a0 = 0.f, a1 = 0.f;
    int j = beg;
    for (; j + 4 <= end; j += 4) {
        const int s0 = srcl[j], s1 = srcl[j + 1], s2 = srcl[j + 2], s3 = srcl[j + 3];
        const float n0 = dv * dinv[sb + s0], n1 = dv * dinv[sb + s1];
        const float n2_ = dv * dinv[sb + s2], n3 = dv * dinv[sb + s3];
        const int r0 = xi[s0], r1 = xi[s1], r2 = xi[s2], r3 = xi[s3];
        const uint v0 = *(const uint*)(emb + (size_t)r0 * 128 + lane * 2);
        const uint v1 = *(const uint*)(emb + (size_t)r1 * 128 + lane * 2);
        const uint v2 = *(const uint*)(emb + (size_t)r2 * 128 + lane * 2);
        const uint v3 = *(const uint*)(emb + (size_t)r3 * 128 + lane * 2);
        a0 += n0 * bf2f(v0 & 0xffff) + n1 * bf2f(v1 & 0xffff) +
              n2_ * bf2f(v2 & 0xffff) + n3 * bf2f(v3 & 0xffff);
        a1 += n0 * bf2f(v0 >> 16) + n1 * bf2f(v1 >> 16) +
              n2_ * bf2f(v2 >> 16) + n3 * bf2f(v3 >> 16);
    }
    for (; j < end; ++j) {
        const int s = srcl[j];
        const float nw = dv * dinv[sb + s];
        const uint v = *(const uint*)(emb + (size_t)xi[s] * 128 + lane * 2);
        a0 += nw * bf2f(v & 0xffff);
        a1 += nw * bf2f(v >> 16);
    }
    *(uint*)(y + (size_t)n2 * 128 + lane * 2) =
        (uint)f2bf(a0) | ((uint)f2bf(a1) << 16);
}

__device__ __forceinline__ void gcn_acc2(const ushort* __restrict__ x,
                                         const float* __restrict__ dinv,
                                         const int* __restrict__ srcl,
                                         int beg, int end, int sb, float dv, int lane,
                                         float& a0, float& a1) {
    int j = beg;
    for (; j + 4 <= end; j += 4) {
        const int s0 = sb + srcl[j], s1 = sb + srcl[j + 1];
        const int s2 = sb + srcl[j + 2], s3 = sb + srcl[j + 3];
        const float n0 = dv * dinv[s0], n1 = dv * dinv[s1];
        const float n2_ = dv * dinv[s2], n3 = dv * dinv[s3];
        const uint v0 = *(const uint*)(x + (size_t)s0 * 128 + lane * 2);
        const uint v1 = *(const uint*)(x + (size_t)s1 * 128 + lane * 2);
        const uint v2 = *(const uint*)(x + (size_t)s2 * 128 + lane * 2);
        const uint v3 = *(const uint*)(x + (size_t)s3 * 128 + lane * 2);
        a0 += n0 * bf2f(v0 & 0xffff) + n1 * bf2f(v1 & 0xffff) +
              n2_ * bf2f(v2 & 0xffff) + n3 * bf2f(v3 & 0xffff);
        a1 += n0 * bf2f(v0 >> 16) + n1 * bf2f(v1 >> 16) +
              n2_ * bf2f(v2 >> 16) + n3 * bf2f(v3 >> 16);
    }
    for (; j < end; ++j) {
        const int s = sb + srcl[j];
        const float nw = dv * dinv[s];
        const uint v = *(const uint*)(x + (size_t)s * 128 + lane * 2);
        a0 += nw * bf2f(v & 0xffff);
        a1 += nw * bf2f(v >> 16);
    }
}

__global__ __launch_bounds__(256) void gcn_agg2(const ushort* __restrict__ x,
                                                const float* __restrict__ dinv,
                                                const int* __restrict__ offs6,
                                                const int* __restrict__ srcl,
                                                ushort* __restrict__ y, int NP) {
    const int n2 = blockIdx.x * 4 + (threadIdx.x >> 6);
    const int lane = threadIdx.x & 63;
    if (n2 >= 2 * NP) return;
    const int side = n2 >= NP;
    const int sb = side ? NP : 0;
    const int beg = offs6[n2], end = offs6[n2 + 1];
    const float dv = dinv[n2];
    float a0 = 0.f, a1 = 0.f;
    gcn_acc2(x, dinv, srcl, beg, end, sb, dv, lane, a0, a1);
    *(uint*)(y + (size_t)n2 * 128 + lane * 2) =
        (uint)f2bf(a0) | ((uint)f2bf(a1) << 16);
}

__global__ __launch_bounds__(256) void gcn_final(const ushort* __restrict__ x,
                                                 const float* __restrict__ dinv,
                                                 const int* __restrict__ offs6,
                                                 const int* __restrict__ srcl,
                                                 const int* __restrict__ offs8,
                                                 const int* __restrict__ offs9,
                                                 ushort* __restrict__ y, int B, int NP) {
    const int g2 = blockIdx.x * 4 + (threadIdx.x >> 6);
    const int lane = threadIdx.x & 63;
    if (g2 >= 2 * B) return;
    const int side = g2 >= B;
    const int gl = g2 - (side ? B : 0);
    const int* bo = side ? offs9 : offs8;
    const int first = bo[gl] - bo[0];
    const int n2 = (side ? NP : 0) + first;
    const int beg = offs6[n2], end = offs6[n2 + 1];
    const float dv = dinv[n2];
    float a0 = 0.f, a1 = 0.f;
    gcn_acc2(x, dinv, srcl, beg, end, side ? NP : 0, dv, lane, a0, a1);
    *(uint*)(y + (size_t)g2 * 128 + lane * 2) =
        (uint)f2bf(a0) | ((uint)f2bf(a1) << 16);
}

// ---------------------------------------------------------------------------
// Cosine similarity: lfrf holds left rows [0,B), right rows [B,2B).
// ---------------------------------------------------------------------------
__global__ __launch_bounds__(256) void cosine_k(const float* __restrict__ lfrf,
                                                float* __restrict__ out, int B) {
    const int g = blockIdx.x * 4 + (threadIdx.x >> 6);
    const int lane = threadIdx.x & 63;
    if (g >= B) return;
    const float2 a = *(const float2*)(lfrf + (size_t)g * 128 + lane * 2);
    const float2 b = *(const float2*)(lfrf + (size_t)(B + g) * 128 + lane * 2);
    float num = a.x * b.x + a.y * b.y;
    float na = a.x * a.x + a.y * a.y;
    float nb = b.x * b.x + b.y * b.y;
#pragma unroll
    for (int o = 32; o > 0; o >>= 1) {
        num += __shfl_down(num, o);
        na += __shfl_down(na, o);
        nb += __shfl_down(nb, o);
    }
    if (lane == 0)
        out[g] = num / (fmaxf(sqrtf(na), 1e-6f) * fmaxf(sqrtf(nb), 1e-6f));
}

// ---------------------------------------------------------------------------
extern "C" void kernel_launch(void* const* d_in, const int* in_sizes, int n_in,
                              void* d_out, int out_size, void* d_ws, size_t ws_size,
                              hipStream_t stream) {
    (void)n_in; (void)ws_size;
    // setup_inputs() dict order
    const float* spec = (const float*)d_in[0];
    const float* tabs[3] = {(const float*)d_in[1], (const float*)d_in[2], (const float*)d_in[3]};
    const float* ontW[3] = {(const float*)d_in[4], (const float*)d_in[8], (const float*)d_in[12]};
    const float* ontAs[3] = {(const float*)d_in[5], (const float*)d_in[9], (const float*)d_in[13]};
    const float* ontAd[3] = {(const float*)d_in[6], (const float*)d_in[10], (const float*)d_in[14]};
    const float* ontB[3] = {(const float*)d_in[7], (const float*)d_in[11], (const float*)d_in[15]};
    const float* gcnW[3] = {(const float*)d_in[16], (const float*)d_in[18], (const float*)d_in[20]};
    const float* gcnB[3] = {(const float*)d_in[17], (const float*)d_in[19], (const float*)d_in[21]};
    const int* e1s[3] = {(const int*)d_in[22], (const int*)d_in[24], (const int*)d_in[26]};
    const int* e2s[3] = {(const int*)d_in[23], (const int*)d_in[25], (const int*)d_in[27]};
    const int* maps[3] = {(const int*)d_in[28], (const int*)d_in[29], (const int*)d_in[30]};
    const int* left_x = (const int*)d_in[31];
    const int* right_x = (const int*)d_in[32];
    const int* left_eg = (const int*)d_in[33];
    const int* right_eg = (const int*)d_in[34];
    const int* left_batch = (const int*)d_in[35];
    const int* right_batch = (const int*)d_in[36];

    int Ms[3] = {in_sizes[1] / HID, in_sizes[2] / HID, in_sizes[3] / HID};
    int E1s[3] = {in_sizes[22] / 2, in_sizes[24] / 2, in_sizes[26] / 2};
    int E2s[3] = {in_sizes[23] / 2, in_sizes[25] / 2, in_sizes[27] / 2};
    int Ls[3] = {in_sizes[28], in_sizes[29], in_sizes[30]};
    const int NP = in_sizes[31];
    const int EP = in_sizes[33] / 2;
    const int B = out_size;
    const long ALL = 1 + (long)Ls[0] + Ls[1] + Ls[2];
    const int Mtot = Ms[0] + Ms[1] + Ms[2];
    const int r1 = Ms[0], r2 = Ms[0] + Ms[1];

    // ---- batched CSR descriptor ----
    CsrDesc dsc;
    int eCnt[10], lCnt[10], nCnt[10];
    for (int i = 0; i < 3; ++i) {
        dsc.esrc[2 * i] = e1s[i];     dsc.edst[2 * i] = e1s[i] + E1s[i];
        dsc.esrc[2 * i + 1] = e2s[i]; dsc.edst[2 * i + 1] = e2s[i] + E2s[i];
        eCnt[2 * i] = E1s[i]; eCnt[2 * i + 1] = E2s[i];
        lCnt[2 * i] = Ms[i];  lCnt[2 * i + 1] = Ms[i];
        nCnt[2 * i] = Ms[i];  nCnt[2 * i + 1] = Ms[i];
    }
    dsc.esrc[6] = left_eg;  dsc.edst[6] = left_eg + EP;  eCnt[6] = EP; lCnt[6] = NP; nCnt[6] = NP;
    dsc.esrc[7] = right_eg; dsc.edst[7] = right_eg + EP; eCnt[7] = EP; lCnt[7] = NP; nCnt[7] = NP;
    dsc.esrc[8] = left_batch;  dsc.edst[8] = left_batch;  eCnt[8] = NP; lCnt[8] = 0; nCnt[8] = B;
    dsc.esrc[9] = right_batch; dsc.edst[9] = right_batch; eCnt[9] = NP; lCnt[9] = 0; nCnt[9] = B;
    dsc.ebase[0] = dsc.lbase[0] = 0;
    int nb_acc = 0;
    for (int i = 0; i < 10; ++i) {
        dsc.ebase[i + 1] = dsc.ebase[i] + eCnt[i];
        dsc.lbase[i + 1] = dsc.lbase[i] + lCnt[i];
        dsc.nbase[i] = nb_acc;
        nb_acc += nCnt[i];
    }
    const int NV = nb_acc;
    dsc.totE = dsc.ebase[10];
    dsc.totL = dsc.lbase[10];
    const int totEntries = dsc.totE + dsc.totL;

    // ---- workspace layout ----
    char* ws = (char*)d_ws;
    size_t off = 0;
    auto alloc = [&](size_t bytes) -> void* {
        off = (off + 255) & ~(size_t)255;
        void* p = ws + off;
        off += bytes;
        return p;
    };
    ushort* allemb = (ushort*)alloc((size_t)ALL * HID * 2);
    float* lfrf = (float*)alloc((size_t)2 * B * HID * 4);
    int* cnt = (int*)alloc((size_t)NV * 4);
    int* offs = (int*)alloc((size_t)(NV + 1) * 4);
    int* pos = (int*)alloc((size_t)totEntries * 4);
    int* srcl = (int*)alloc((size_t)totEntries * 4);
    int* bsum = (int*)alloc(1025 * 4);
    float* dinv = (float*)alloc((size_t)2 * NP * 4);
    float* as = (float*)alloc((size_t)Mtot * 4);
    float* ad = (float*)alloc((size_t)Mtot * 4);
    float* wa = (float*)alloc(3 * 256 * 4);
    ushort* y3 = (ushort*)alloc((size_t)2 * B * HID * 2);
    // region A: yo (ontology agg out, bf16 Mtot rows) / xb (patient, 2NP rows)
    const size_t szA = (size_t)2 * NP * HID * 2;
    ushort* bufA = (ushort*)alloc(szA);
    // region B: oE (ontology fp32 Mtot rows) / yb (patient bf16 2NP rows)
    const size_t szB_oE = (size_t)Mtot * HID * 4;
    const size_t szB = szB_oE > szA ? szB_oE : szA;
    char* bufB = (char*)alloc(szB);
    ushort* yo = bufA;                 // [Mtot x 128] bf16
    ushort* xb = bufA;                 // [2NP x 128] bf16 (after ontology)
    float* oE = (float*)bufB;          // [Mtot x 128] fp32
    ushort* yb = (ushort*)bufB;        // [2NP x 128] bf16 (after build_emb)

    auto scan_excl = [&](const int* in, int* out, int n) {
        const int nb = cdiv_i(n, 1024);
        scan_tile<<<nb, 1024, 0, stream>>>(in, out, bsum, n);
        scan_single<<<1, 1024, 0, stream>>>(bsum, nb);
        scan_add<<<cdiv_i(n + 1, 256), 256, 0, stream>>>(out, bsum, n, nb);
    };

    // ---- CSR build ----
    hipMemsetAsync(cnt, 0, (size_t)NV * 4, stream);
    csr_count_b<<<cdiv_i(totEntries, 256), 256, 0, stream>>>(dsc, cnt, pos);
    scan_excl(cnt, offs, NV);
    csr_fill_b<<<cdiv_i(totEntries, 256), 256, 0, stream>>>(dsc, offs, pos, srcl);
    deg_inv<<<cdiv_i(2 * NP, 256), 256, 0, stream>>>(cnt + dsc.nbase[6], dinv, 2 * NP);

    // ---- ontology: 2 batched GAT layers over combined 3-graph space ----
    wvec_all<<<3, 256, 0, stream>>>(P3{ontW[0], ontW[1], ontW[2]},
                                    P3{ontAs[0], ontAs[1], ontAs[2]},
                                    P3{ontAd[0], ontAd[1], ontAd[2]}, wa);
    GOnto go;
    go.W0 = ontW[0]; go.W1 = ontW[1]; go.W2 = ontW[2];
    go.b0 = ontB[0]; go.b1 = ontB[1]; go.b2 = ontB[2];
    go.bs1 = cdiv_i(Ms[0], 128);
    go.bs2 = go.bs1 + cdiv_i(Ms[1], 128);
    const int totBlk = go.bs2 + cdiv_i(Ms[2], 128);
    go.r1 = r1; go.r2 = r2; go.r3 = Mtot;

    const OntoX oxT{tabs[0], tabs[1], tabs[2], r1, r2};
    const OntoX oxE{oE, oE + (size_t)r1 * 128, oE + (size_t)r2 * 128, r1, r2};
    for (int layer = 0; layer < 2; ++layer) {
        const OntoX& ox = (layer == 0) ? oxT : oxE;
        const OntoG og{dsc.nbase[0 + layer], dsc.nbase[2 + layer], dsc.nbase[4 + layer]};
        att_all<<<cdiv_i(Mtot, 4), 256, 0, stream>>>(ox, wa, as, ad, Mtot);
        gat_all<<<cdiv_i(Mtot, 4), 256, 0, stream>>>(ox, as, ad, offs, srcl, og, yo, Mtot);
        gemm_onto<<<totBlk, 256, 0, stream>>>(yo, go, oE);
    }

    EmbD ed;
    ed.spec = spec; ed.oE = oE;
    ed.m0 = maps[0]; ed.m1 = maps[1]; ed.m2 = maps[2];
    ed.lb2 = 1 + Ls[0]; ed.lb3 = 1 + Ls[0] + Ls[1];
    ed.r1 = r1; ed.r2 = r2; ed.ALLr = ALL;
    build_emb<<<cdiv_i(ALL * 16, 256), 256, 0, stream>>>(ed, allemb);

    // ---- patient: 3 GCN layers, both sides fused ----
    const int* offs6 = offs + dsc.nbase[6];
    const int* offs8 = offs + dsc.nbase[8];
    const int* offs9 = offs + dsc.nbase[9];
    gcn_agg1<<<cdiv_i(2 * NP, 4), 256, 0, stream>>>(allemb, left_x, right_x, dinv,
                                                    offs6, srcl, yb, NP);
    gemm_gcn<ushort><<<cdiv_i(2 * NP, 128), 256, 0, stream>>>(yb, gcnW[0], gcnB[0], xb, 2 * NP);
    gcn_agg2<<<cdiv_i(2 * NP, 4), 256, 0, stream>>>(xb, dinv, offs6, srcl, yb, NP);
    gemm_gcn<ushort><<<cdiv_i(2 * NP, 128), 256, 0, stream>>>(yb, gcnW[1], gcnB[1], xb, 2 * NP);
    gcn_final<<<cdiv_i(2 * B, 4), 256, 0, stream>>>(xb, dinv, offs6, srcl, offs8, offs9,
                                                    y3, B, NP);
    gemm_gcn<float><<<cdiv_i(2 * B, 128), 256, 0, stream>>>(y3, gcnW[2], gcnB[2], lfrf, 2 * B);

    cosine_k<<<cdiv_i(B, 4), 256, 0, stream>>>(lfrf, (float*)d_out, B);
}